// Round 5
// baseline (163.797 us; speedup 1.0000x reference)
//
#include <hip/hip_runtime.h>
#include <hip/hip_cooperative_groups.h>

namespace cg = cooperative_groups;

// Problem constants (from reference setup_inputs)
#define BB    16
#define CC    80
#define HH    160
#define WW    160
#define NN    32
#define HW_   (HH * WW)          // 25600
#define CHW   (CC * HH * WW)     // 2,048,000
#define GRIDX 64                 // blocks per batch (block (0,0) is the gt block)
#define N4    (CHW / 4)          // 512000 float4s per batch

// Precise softplus (gt path only — 512 uses)
__device__ __forceinline__ float softplus_precise(float x) {
    return fmaxf(x, 0.0f) + log1pf(expf(-fabsf(x)));
}

// Lean softplus: ln(1+e^x) = ln2 * log2(1 + exp2(x*log2e)). OK for x < ~88.
__device__ __forceinline__ float softplus_fast(float x) {
    float e = __builtin_amdgcn_exp2f(x * 1.44269504088896f);
    return 0.69314718055995f * __builtin_amdgcn_logf(1.0f + e);
}

// Single cooperative kernel.
// Blocks (x,b) with (x>0 || b>0): streaming softplus partial for batch b.
// Block (0,0): all gt work (geometry, dedup, bbox L1, pos BCE) concurrently,
// then after grid.sync() combines partials and finalizes.
__global__ void __launch_bounds__(256, 4)
detection_loss_fused(const float* __restrict__ cls, const float* __restrict__ bbox,
                     const float* __restrict__ gtb, const int* __restrict__ gtl,
                     float* __restrict__ ws, float* __restrict__ out) {
    cg::grid_group grid = cg::this_grid();
    const int x = blockIdx.x;   // 0..63
    const int b = blockIdx.y;   // 0..15
    const int t = threadIdx.x;  // 0..255

    __shared__ float red[4];
    // gt-block state (persists across grid.sync within the block)
    __shared__ int   keys[BB * NN];      // dedup keys, key = lbl*HW_ + gy*WW + gx
    __shared__ int   s_gxy[BB * NN];     // gy*WW+gx
    __shared__ float s_x1[BB * NN], s_y1[BB * NN], s_x2[BB * NN], s_y2[BB * NN];
    __shared__ float s_pos_bce[BB], s_pos_sp[BB];
    __shared__ int   s_pos_cnt[BB];
    __shared__ float s_total[BB];
    __shared__ float s_bbox_total;

    const bool gt_block = (x == 0) && (b == 0);

    if (!gt_block) {
        // ---- streaming softplus partial for batch b ----
        const int nb = (b == 0) ? (GRIDX - 1) : GRIDX;   // batch 0 has 63 blocks
        const int xi = (b == 0) ? (x - 1) : x;
        const float4* __restrict__ p =
            reinterpret_cast<const float4*>(cls + (size_t)b * CHW);
        const int tid = xi * 256 + t;
        const int stride = nb * 256;
        float a0 = 0.0f, a1 = 0.0f;
        for (int i = tid; i < N4; i += stride) {
            float4 v = p[i];
            a0 += softplus_fast(v.x) + softplus_fast(v.y);
            a1 += softplus_fast(v.z) + softplus_fast(v.w);
        }
        float acc = a0 + a1;
        for (int off = 32; off > 0; off >>= 1)
            acc += __shfl_down(acc, off, 64);
        const int lane = t & 63, wid = t >> 6;
        if (lane == 0) red[wid] = acc;
        __syncthreads();
        if (t == 0)
            ws[b * GRIDX + x] = red[0] + red[1] + red[2] + red[3];
    } else {
        // ---- gt block: geometry + dedup + bbox L1 + pos BCE ----
        if (t == 0) { ws[0] = 0.0f; }    // unused partial slot
        if (t < BB) {
            s_pos_bce[t] = 0.0f; s_pos_sp[t] = 0.0f;
            s_pos_cnt[t] = 0;    s_total[t] = 0.0f;
        }
        __syncthreads();

        // pass 1: keys + geometry (2 gts per thread)
        #pragma unroll
        for (int g2 = 0; g2 < 2; ++g2) {
            const int gi = t + g2 * 256;       // 0..511
            const float* g = gtb + (size_t)gi * 4;
            const float x1 = g[0] * (float)WW;
            const float y1 = g[1] * (float)HH;
            const float x2 = g[2] * (float)WW;
            const float y2 = g[3] * (float)HH;
            const float cx = fminf(fmaxf((x1 + x2) * 0.5f, 0.0f), (float)(WW - 1));
            const float cy = fminf(fmaxf((y1 + y2) * 0.5f, 0.0f), (float)(HH - 1));
            const int gx = (int)cx;
            const int gy = (int)cy;
            const int lbl = gtl[gi];
            s_x1[gi] = x1; s_y1[gi] = y1; s_x2[gi] = x2; s_y2[gi] = y2;
            s_gxy[gi] = gy * WW + gx;
            keys[gi] = lbl * HW_ + gy * WW + gx;
        }
        __syncthreads();

        // pass 2: bbox L1 (all gts) + pos BCE (unique gts)
        float bl = 0.0f;
        #pragma unroll
        for (int g2 = 0; g2 < 2; ++g2) {
            const int gi = t + g2 * 256;
            const int gb = gi >> 5;            // batch of this gt (NN==32)
            const int gxy = s_gxy[gi];
            const int key = keys[gi];
            const float* bp = bbox + (size_t)gb * 4 * HW_ + gxy;
            bl += 0.25f * (fabsf(bp[0 * HW_] - s_x1[gi]) +
                           fabsf(bp[1 * HW_] - s_y1[gi]) +
                           fabsf(bp[2 * HW_] - s_x2[gi]) +
                           fabsf(bp[3 * HW_] - s_y2[gi]));
            bool owner = true;
            for (int j = gb * NN; j < gi; ++j)
                if (keys[j] == key) { owner = false; break; }
            if (owner) {
                // cls index: (gb*CC + lbl)*HW_ + gxy == gb*CHW + key
                const float xv = cls[(size_t)gb * CHW + key];
                const float sp = softplus_precise(xv);
                atomicAdd(&s_pos_bce[gb], sp - xv);
                atomicAdd(&s_pos_sp[gb], sp);
                atomicAdd(&s_pos_cnt[gb], 1);
            }
        }
        // block reduce bbox loss (256 threads)
        for (int off = 32; off > 0; off >>= 1)
            bl += __shfl_down(bl, off, 64);
        const int lane = t & 63, wid = t >> 6;
        if (lane == 0) red[wid] = bl;
        __syncthreads();
        if (t == 0) s_bbox_total = red[0] + red[1] + red[2] + red[3];
    }

    grid.sync();

    if (gt_block) {
        // combine 1024 partials: 256 threads x 4, batch = idx/64
        #pragma unroll
        for (int k = 0; k < 4; ++k) {
            const int i = t + k * 256;
            atomicAdd(&s_total[i >> 6], ws[i]);
        }
        __syncthreads();
        if (t == 0) {
            float pos_cls = 0.0f, neg_cls = 0.0f;
            for (int bi = 0; bi < BB; ++bi) {
                const float pc = (float)s_pos_cnt[bi];
                const float nc = (float)CHW - pc;
                const float neg_sum = s_total[bi] - s_pos_sp[bi];
                pos_cls += s_pos_bce[bi] / pc;
                neg_cls += neg_sum / nc;
            }
            const float num_pos = (float)(BB * NN);   // 512
            pos_cls /= num_pos;
            const float bbox_loss = s_bbox_total / num_pos;
            neg_cls /= (float)BB;
            const float cls_loss = pos_cls + 0.25f * neg_cls;
            const float total = 0.5f * cls_loss + 7.5f * bbox_loss + 1e-6f;
            out[0] = total;
            out[1] = cls_loss;
            out[2] = bbox_loss;
        }
    }
}

extern "C" void kernel_launch(void* const* d_in, const int* in_sizes, int n_in,
                              void* d_out, int out_size, void* d_ws, size_t ws_size,
                              hipStream_t stream) {
    const float* cls  = (const float*)d_in[0];   // (16,80,160,160) f32
    const float* bbox = (const float*)d_in[1];   // (16,4,160,160) f32
    const float* gtb  = (const float*)d_in[2];   // (16,32,4) f32
    const int*   gtl  = (const int*)d_in[3];     // (16,32) int
    float* out = (float*)d_out;
    float* ws  = (float*)d_ws;                   // BB*GRIDX partials (f32)

    void* args[] = { (void*)&cls, (void*)&bbox, (void*)&gtb, (void*)&gtl,
                     (void*)&ws, (void*)&out };
    hipLaunchCooperativeKernel((const void*)detection_loss_fused,
                               dim3(GRIDX, BB), dim3(256),
                               args, 0, stream);
}

// Round 6
// 28.853 us; speedup vs baseline: 5.6768x; 5.6768x over previous
//
#include <hip/hip_runtime.h>

// Problem constants (from reference setup_inputs)
#define BB    16
#define CC    80
#define HH    160
#define WW    160
#define NN    32
#define HW_   (HH * WW)          // 25600
#define CHW   (CC * HH * WW)     // 2,048,000
#define GRIDX 256                // streaming blocks per batch
#define N4    (CHW / 4)          // 512000 float4s per batch
#define GOFF  (GRIDX * BB)       // ws offset of gt results (4096)

// ws layout: [0 .. 4095] streaming partials (b*GRIDX + x)
//            [GOFF+ 0..15] pos_bce   [GOFF+16..31] pos_sp
//            [GOFF+32..47] pos_cnt   [GOFF+48]     bbox_total

// Precise softplus (gt path only — 512 uses)
__device__ __forceinline__ float softplus_precise(float x) {
    return fmaxf(x, 0.0f) + log1pf(expf(-fabsf(x)));
}

// Lean softplus: ln(1+e^x) = ln2 * log2(1 + exp2(x*log2e)). OK for x < ~88.
__device__ __forceinline__ float softplus_fast(float x) {
    float e = __builtin_amdgcn_exp2f(x * 1.44269504088896f);
    return 0.69314718055995f * __builtin_amdgcn_logf(1.0f + e);
}

// Kernel A: blocks x<GRIDX stream softplus partials for batch b.
// Block (GRIDX, 0) does all gt work concurrently (latency hidden under stream).
__global__ void __launch_bounds__(256)
stream_and_gt(const float* __restrict__ cls, const float* __restrict__ bbox,
              const float* __restrict__ gtb, const int* __restrict__ gtl,
              float* __restrict__ ws) {
    const int x = blockIdx.x;   // 0..GRIDX  (GRIDX => gt block when b==0)
    const int b = blockIdx.y;   // 0..15
    const int t = threadIdx.x;  // 0..255

    __shared__ float red[4];

    if (x < GRIDX) {
        // ---- streaming softplus partial for batch b ----
        const float4* __restrict__ p =
            reinterpret_cast<const float4*>(cls + (size_t)b * CHW);
        const int tid = x * 256 + t;
        float a0 = 0.0f, a1 = 0.0f;
        for (int i = tid; i < N4; i += GRIDX * 256) {
            float4 v = p[i];
            a0 += softplus_fast(v.x) + softplus_fast(v.y);
            a1 += softplus_fast(v.z) + softplus_fast(v.w);
        }
        float acc = a0 + a1;
        for (int off = 32; off > 0; off >>= 1)
            acc += __shfl_down(acc, off, 64);
        const int lane = t & 63, wid = t >> 6;
        if (lane == 0) red[wid] = acc;
        __syncthreads();
        if (t == 0)
            ws[b * GRIDX + x] = red[0] + red[1] + red[2] + red[3];
        return;
    }
    if (b != 0) return;   // only one gt block

    // ---- gt block: geometry + dedup + bbox L1 + pos BCE ----
    __shared__ int   keys[BB * NN];
    __shared__ int   s_gxy[BB * NN];
    __shared__ float s_x1[BB * NN], s_y1[BB * NN], s_x2[BB * NN], s_y2[BB * NN];
    __shared__ float s_pos_bce[BB], s_pos_sp[BB];
    __shared__ int   s_pos_cnt[BB];

    if (t < BB) { s_pos_bce[t] = 0.0f; s_pos_sp[t] = 0.0f; s_pos_cnt[t] = 0; }
    __syncthreads();

    // pass 1: keys + geometry (2 gts per thread)
    #pragma unroll
    for (int g2 = 0; g2 < 2; ++g2) {
        const int gi = t + g2 * 256;       // 0..511
        const float* g = gtb + (size_t)gi * 4;
        const float x1 = g[0] * (float)WW;
        const float y1 = g[1] * (float)HH;
        const float x2 = g[2] * (float)WW;
        const float y2 = g[3] * (float)HH;
        const float cx = fminf(fmaxf((x1 + x2) * 0.5f, 0.0f), (float)(WW - 1));
        const float cy = fminf(fmaxf((y1 + y2) * 0.5f, 0.0f), (float)(HH - 1));
        const int gx = (int)cx;
        const int gy = (int)cy;
        const int lbl = gtl[gi];
        s_x1[gi] = x1; s_y1[gi] = y1; s_x2[gi] = x2; s_y2[gi] = y2;
        s_gxy[gi] = gy * WW + gx;
        keys[gi] = lbl * HW_ + gy * WW + gx;
    }
    __syncthreads();

    // pass 2: bbox L1 (all gts) + pos BCE (unique gts per batch)
    float bl = 0.0f;
    #pragma unroll
    for (int g2 = 0; g2 < 2; ++g2) {
        const int gi = t + g2 * 256;
        const int gb = gi >> 5;            // batch of this gt (NN==32)
        const int gxy = s_gxy[gi];
        const int key = keys[gi];
        const float* bp = bbox + (size_t)gb * 4 * HW_ + gxy;
        bl += 0.25f * (fabsf(bp[0 * HW_] - s_x1[gi]) +
                       fabsf(bp[1 * HW_] - s_y1[gi]) +
                       fabsf(bp[2 * HW_] - s_x2[gi]) +
                       fabsf(bp[3 * HW_] - s_y2[gi]));
        bool owner = true;
        for (int j = gb * NN; j < gi; ++j)
            if (keys[j] == key) { owner = false; break; }
        if (owner) {
            // cls index: (gb*CC + lbl)*HW_ + gxy == gb*CHW + key
            const float xv = cls[(size_t)gb * CHW + key];
            const float sp = softplus_precise(xv);
            atomicAdd(&s_pos_bce[gb], sp - xv);
            atomicAdd(&s_pos_sp[gb], sp);
            atomicAdd(&s_pos_cnt[gb], 1);
        }
    }
    for (int off = 32; off > 0; off >>= 1)
        bl += __shfl_down(bl, off, 64);
    const int lane = t & 63, wid = t >> 6;
    if (lane == 0) red[wid] = bl;
    __syncthreads();

    if (t < BB) {
        ws[GOFF +      t] = s_pos_bce[t];
        ws[GOFF + 16 + t] = s_pos_sp[t];
        ws[GOFF + 32 + t] = (float)s_pos_cnt[t];
    }
    if (t == 0) ws[GOFF + 48] = red[0] + red[1] + red[2] + red[3];
}

// Kernel B: tiny combine. 256 threads sum 4096 partials; t==0 finalizes.
__global__ void __launch_bounds__(256)
finalize_loss(const float* __restrict__ ws, float* __restrict__ out) {
    const int t = threadIdx.x;
    __shared__ float s_total[BB];
    if (t < BB) s_total[t] = 0.0f;
    __syncthreads();

    const int b = t >> 4, i = t & 15;       // 16 threads per batch
    const float* w = ws + b * GRIDX;
    float s = 0.0f;
    #pragma unroll
    for (int k = 0; k < GRIDX / 16; ++k) s += w[i + k * 16];
    atomicAdd(&s_total[b], s);
    __syncthreads();

    if (t == 0) {
        float pos_cls = 0.0f, neg_cls = 0.0f;
        for (int bi = 0; bi < BB; ++bi) {
            const float pc = ws[GOFF + 32 + bi];
            const float nc = (float)CHW - pc;
            const float neg_sum = s_total[bi] - ws[GOFF + 16 + bi];
            pos_cls += ws[GOFF + bi] / pc;
            neg_cls += neg_sum / nc;
        }
        const float num_pos = (float)(BB * NN);   // 512
        pos_cls /= num_pos;
        const float bbox_loss = ws[GOFF + 48] / num_pos;
        neg_cls /= (float)BB;
        const float cls_loss = pos_cls + 0.25f * neg_cls;
        const float total = 0.5f * cls_loss + 7.5f * bbox_loss + 1e-6f;
        out[0] = total;
        out[1] = cls_loss;
        out[2] = bbox_loss;
    }
}

extern "C" void kernel_launch(void* const* d_in, const int* in_sizes, int n_in,
                              void* d_out, int out_size, void* d_ws, size_t ws_size,
                              hipStream_t stream) {
    const float* cls  = (const float*)d_in[0];   // (16,80,160,160) f32
    const float* bbox = (const float*)d_in[1];   // (16,4,160,160) f32
    const float* gtb  = (const float*)d_in[2];   // (16,32,4) f32
    const int*   gtl  = (const int*)d_in[3];     // (16,32) int
    float* out = (float*)d_out;
    float* ws  = (float*)d_ws;

    dim3 gridA(GRIDX + 1, BB);   // +1 column; only (GRIDX,0) does gt work
    stream_and_gt<<<gridA, 256, 0, stream>>>(cls, bbox, gtb, gtl, ws);

    finalize_loss<<<1, 256, 0, stream>>>(ws, out);
}